// Round 3
// baseline (330.536 us; speedup 1.0000x reference)
//
#include <hip/hip_runtime.h>
#include <math.h>

#define NCONF  64
#define NATOMS 256
#define NCOEFF 45
#define NAOV   12
#define NPAIR  66
#define RAD    384    // 12 * 32
#define ANG    4224   // 66 * 64
#define TOT    4608

// linspace(0.5, 3.5, 16); shfR == shfS (same bounds, same eta=16) -> fold with &15
__constant__ float c_shfS[16] = {
    0.5f, 0.7f, 0.9f, 1.1f, 1.3f, 1.5f, 1.7f, 1.9f,
    2.1f, 2.3f, 2.5f, 2.7f, 2.9f, 3.1f, 3.3f, 3.5f
};
// linspace(0.5, 3.5, 8)
__constant__ float c_shfA[8] = {
    0.5f, 0.92857142857f, 1.35714285714f, 1.78571428571f,
    2.21428571429f, 2.64285714286f, 3.07142857143f, 3.5f
};
// cos/sin of shfZ = pi/16 + k*pi/8; cos(acos(c)-z) = c*cosZ + sqrt(1-c^2)*sinZ
__constant__ float c_cosZ[8] = {
     0.98078528f,  0.83146961f,  0.55557023f,  0.19509032f,
    -0.19509032f, -0.55557023f, -0.83146961f, -0.98078528f
};
__constant__ float c_sinZ[8] = {
    0.19509032f, 0.55557023f, 0.83146961f, 0.98078528f,
    0.98078528f, 0.83146961f, 0.55557023f, 0.19509032f
};

// One wave = one atom. No LDS, no barriers, no vmcnt(0) drains.
// lane -> (z = lane>>3, a = lane&7) cell of every pair's 8x8 angular block.
__global__ __launch_bounds__(256, 4)
void OrbitalAEVComputer_40492951667225_kernel(const float* __restrict__ coef,
                                              float* __restrict__ out) {
    const int lane = threadIdx.x & 63;
    // wave-uniform atom index; force scalar so coef loads become s_load
    int atom = (int)(blockIdx.x * 4 + (threadIdx.x >> 6));
    atom = __builtin_amdgcn_readfirstlane(atom);
    const float* c = coef + (size_t)atom * NCOEFF;

    // ---- all 12 AOV vectors in registers (wave-uniform values) ----
    float dist[NAOV], nx[NAOV], ny[NAOV], nz[NAOV];
#pragma unroll
    for (int p = 0; p < NAOV; ++p) {
        float x, y, z;
        if (p < 4) {
            x = c[9 + 3 * p]; y = c[10 + 3 * p]; z = c[11 + 3 * p];
        } else {
            const int r = (p - 4) >> 1, h = (p - 4) & 1;
            const float* b = c + 21 + 6 * r;
            // d-column permutation [0,2,5,4,3,1] split into two 3-vectors
            if (h == 0) { x = b[0]; y = b[2]; z = b[5]; }
            else        { x = b[4]; y = b[3]; z = b[1]; }
        }
        const float d = sqrtf(x * x + y * y + z * z);
        const bool zm = (fabsf(x) < 1e-12f) && (fabsf(y) < 1e-12f) && (fabsf(z) < 1e-12f);
        const float inv = zm ? 0.0f : 1.0f / d;
        dist[p] = d; nx[p] = x * inv; ny[p] = y * inv; nz[p] = z * inv;
    }

    float* o = out + (size_t)atom * TOT;

    // ---- radial: 384 elems = 6 chunks of 64; k = lane&15 is chunk-invariant ----
    const float shf = c_shfS[lane & 15];
#pragma unroll
    for (int ch = 0; ch < 6; ++ch) {
        const float d = (lane & 32) ? dist[2 * ch + 1] : dist[2 * ch];
        const float dd = d - shf;
        __builtin_nontemporal_store(__expf(-16.0f * dd * dd), o + ch * 64 + lane);
    }

    // ---- angular: pair q -> 64 contiguous elems, one per lane ----
    const float cz = c_cosZ[lane >> 3];
    const float sz = c_sinZ[lane >> 3];
    const float sa = c_shfA[lane & 7];
    float* oa = o + RAD + lane;

    int q = 0;
#pragma unroll
    for (int i = 0; i < NAOV - 1; ++i) {
#pragma unroll
        for (int j = i + 1; j < NAOV; ++j) {
            const float cang = nx[i] * nx[j] + ny[i] * ny[j] + nz[i] * nz[j];
            const float c95 = 0.95f * cang;                        // cos(angle)
            const float sn  = sqrtf(fmaxf(1.0f - c95 * c95, 0.0f)); // sin(angle) >= 0
            const float cosa = fmaf(c95, cz, sn * sz);             // cos(angle - shfZ)
            float x = 0.5f + 0.5f * cosa;                          // in [0,1]
            x = x * x; x = x * x; x = x * x; x = x * x; x = x * x; // ^32
            const float dd = 0.5f * (dist[i] + dist[j]) - sa;
            const float f2 = __expf(-8.0f * dd * dd);
            __builtin_nontemporal_store(2.0f * x * f2, oa + q * 64);
            ++q;
        }
    }
}

extern "C" void kernel_launch(void* const* d_in, const int* in_sizes, int n_in,
                              void* d_out, int out_size, void* d_ws, size_t ws_size,
                              hipStream_t stream) {
    const float* coef = (const float*)d_in[0];
    float* out = (float*)d_out;
    // 16384 atoms, 1 wave each, 4 waves per 256-thread block -> 4096 blocks
    OrbitalAEVComputer_40492951667225_kernel<<<dim3(NCONF * NATOMS / 4), dim3(256), 0, stream>>>(coef, out);
}